// Round 5
// baseline (62.867 us; speedup 1.0000x reference)
//
#include <hip/hip_runtime.h>
#include <math.h>

#define BB 8
#define SS 64
#define NN 512
#define EE 32
#define IT 8

__device__ __forceinline__ unsigned short f2bf(float f) {
    union { float f; unsigned u; } v; v.f = f;
    unsigned r = v.u + 0x7fffu + ((v.u >> 16) & 1u);   // RTNE
    return (unsigned short)(r >> 16);
}

__device__ __forceinline__ float qsum(float v) {      // sum over 4-lane quad (VALU pipe)
    v += __int_as_float(__builtin_amdgcn_mov_dpp(__float_as_int(v), 0xB1, 0xF, 0xF, true));
    v += __int_as_float(__builtin_amdgcn_mov_dpp(__float_as_int(v), 0x4E, 0xF, 0xF, true));
    return v;
}

// proj: tip[b][e][n] = ti' = x^T W_i^T + b_w, tjp[b][e][n] = tj   (layout B,E,N)
//       cip[b][n] = sum_e Wa[e]*ti'[n][e];  djp[b][n] = sum_e Wa[e]*tj[n][e]
__global__ __launch_bounds__(256) void proj_kernel(
    const float* __restrict__ x, const float* __restrict__ W,
    const float* __restrict__ b_w, const float* __restrict__ Wa,
    float* __restrict__ tip, float* __restrict__ tjp,
    float* __restrict__ cip, float* __restrict__ djp)
{
    __shared__ float sW[SS][65];
    const int t = threadIdx.x;
    const int wg = ((blockIdx.x & 7) << 5) | (blockIdx.x >> 3);  // XCD swizzle (256=8*32)
    const int b = wg >> 5;
    const int n0 = (wg & 31) << 4;

#pragma unroll
    for (int r = 0; r < 4; ++r) {   // stage W (4096 floats) as [s][eo]
        int idx = r * 1024 + t * 4;
        float4 w4 = *(const float4*)(W + idx);
        int e = idx >> 7;
        int sp = idx & 127;
        int eo = ((sp >> 6) << 5) | e;   // 0..31 ti, 32..63 tj
        int s0 = sp & 63;
        sW[s0 + 0][eo] = w4.x;
        sW[s0 + 1][eo] = w4.y;
        sW[s0 + 2][eo] = w4.z;
        sW[s0 + 3][eo] = w4.w;
    }
    __syncthreads();

    const int eo = t & 63;
    const int ng = t >> 6;
    const float* xb = x + (size_t)b * SS * NN + n0 + (ng << 2);
    float a0 = 0.f, a1 = 0.f, a2 = 0.f, a3 = 0.f;
#pragma unroll 8
    for (int s = 0; s < SS; ++s) {
        float wv = sW[s][eo];                               // conflict-free
        float4 xv = *(const float4*)(xb + (size_t)s * NN);  // wave-uniform bcast
        a0 = fmaf(wv, xv.x, a0);
        a1 = fmaf(wv, xv.y, a1);
        a2 = fmaf(wv, xv.z, a2);
        a3 = fmaf(wv, xv.w, a3);
    }
    const int e = eo & 31;
    const bool isI = eo < EE;
    float bias = isI ? b_w[e] : 0.f;
    a0 += bias; a1 += bias; a2 += bias; a3 += bias;
    float* dst = isI ? tip : tjp;
    *(float4*)(dst + ((size_t)(b * EE + e)) * NN + n0 + (ng << 2)) =
        make_float4(a0, a1, a2, a3);

    // rank-1 terms: reduce wa*val over each 32-lane half (xor<32 keeps halves apart)
    float wa = Wa[e];
    float r0 = wa * a0, r1 = wa * a1, r2 = wa * a2, r3 = wa * a3;
#pragma unroll
    for (int off = 1; off <= 16; off <<= 1) {
        r0 += __shfl_xor(r0, off);
        r1 += __shfl_xor(r1, off);
        r2 += __shfl_xor(r2, off);
        r3 += __shfl_xor(r3, off);
    }
    if (eo == 0)
        *(float4*)(cip + (size_t)b * NN + n0 + (ng << 2)) = make_float4(r0, r1, r2, r3);
    if (eo == 32)
        *(float4*)(djp + (size_t)b * NN + n0 + (ng << 2)) = make_float4(r0, r1, r2, r3);
}

// attn: block = (b, 8-i tile), 512 threads, 2 blocks/CU. LDS ~26 KB.
__global__ __launch_bounds__(512, 4) void attn_kernel(
    const float* __restrict__ x,
    const float* __restrict__ tip,
    const float* __restrict__ tjp,
    const float* __restrict__ cip,
    const float* __restrict__ djp,
    const float* __restrict__ Wa,
    float* __restrict__ out0,
    float* __restrict__ out1)
{
    __shared__ __align__(16) unsigned scT[NN * 4];   // 8 KB: row j = 8 bf16 (i 0..7)
    __shared__ __align__(16) float hp[65 * 68];      // [s][w*8+i], s-stride 68 (17.7 KB)
    __shared__ float s_inv[IT];

    const int t = threadIdx.x;
    const int wg = ((blockIdx.x & 7) << 6) | (blockIdx.x >> 3);  // XCD swizzle (512=8*64)
    const int b = wg >> 6;
    const int i0 = (wg & 63) << 3;

    // ---- scores: thread owns j = t; ti/Wa via scalar loads (SGPR operands) ----
    const float* tjb = tjp + (size_t)b * EE * NN + t;
    const float* tib = tip + (size_t)b * EE * NN + i0;   // block-uniform -> s_load
    float acc[IT];
#pragma unroll
    for (int i = 0; i < IT; ++i) acc[i] = 0.f;

#pragma unroll
    for (int e = 0; e < EE; ++e) {
        float tjv = tjb[(size_t)e * NN];                 // coalesced L2
        float wa = Wa[e];                                // uniform
#pragma unroll
        for (int i = 0; i < IT; ++i) {
            float p = tib[e * NN + i] + tjv;             // sgpr + vgpr
            acc[i] = fmaf(fabsf(p), wa, acc[i]);         // |p| input-modifier
        }
    }

    // epilogue: sc = 0.4*acc + 0.6*(ci + dj); no-max softmax (|sc| < ~10)
    float dj = djp[(size_t)b * NN + t];
    const float* cib = cip + (size_t)b * NN + i0;        // uniform
    float pr[IT];
#pragma unroll
    for (int i = 0; i < IT; ++i) {
        float sc = fmaf(0.4f, acc[i], 0.6f * (cib[i] + dj));
        pr[i] = __expf(sc);
    }

    // pack 8 bf16 -> one 16B row of scT
    {
        unsigned p0 = f2bf(pr[0]) | ((unsigned)f2bf(pr[1]) << 16);
        unsigned p1 = f2bf(pr[2]) | ((unsigned)f2bf(pr[3]) << 16);
        unsigned p2 = f2bf(pr[4]) | ((unsigned)f2bf(pr[5]) << 16);
        unsigned p3 = f2bf(pr[6]) | ((unsigned)f2bf(pr[7]) << 16);
        uint4 pk; pk.x = p0; pk.y = p1; pk.z = p2; pk.w = p3;
        *(uint4*)&scT[t << 2] = pk;
    }
    __syncthreads();

    // ---- PV: wave w owns j in [w*64, w*64+64); lane = (jw, sh) ----
    const int jw = t & 3;
    const int sh = (t >> 2) & 15;
    const int w = t >> 6;

    float pacc[4][8];
    float pones[8];
#pragma unroll
    for (int r = 0; r < 4; ++r)
#pragma unroll
        for (int i = 0; i < 8; ++i) pacc[r][i] = 0.f;
#pragma unroll
    for (int i = 0; i < 8; ++i) pones[i] = 0.f;

    const float* xb = x + (size_t)b * SS * NN;
#pragma unroll
    for (int c4 = 0; c4 < 4; ++c4) {
        const int jseg = (w << 6) + (c4 << 4) + (jw << 2);
        float psc[4][8];
#pragma unroll
        for (int v = 0; v < 4; ++v) {                    // conflict-free b128 (bcast x16)
            uint4 d = *(const uint4*)&scT[(jseg + v) << 2];
            psc[v][0] = __uint_as_float(d.x << 16);
            psc[v][1] = __uint_as_float(d.x & 0xffff0000u);
            psc[v][2] = __uint_as_float(d.y << 16);
            psc[v][3] = __uint_as_float(d.y & 0xffff0000u);
            psc[v][4] = __uint_as_float(d.z << 16);
            psc[v][5] = __uint_as_float(d.z & 0xffff0000u);
            psc[v][6] = __uint_as_float(d.w << 16);
            psc[v][7] = __uint_as_float(d.w & 0xffff0000u);
        }
#pragma unroll
        for (int r = 0; r < 4; ++r) {
            int s = (sh << 2) + r;
            float4 xv = *(const float4*)(xb + (size_t)s * NN + jseg);  // L2 direct
#pragma unroll
            for (int i = 0; i < 8; ++i) {
                float a = fmaf(xv.x, psc[0][i], pacc[r][i]);
                a = fmaf(xv.y, psc[1][i], a);
                a = fmaf(xv.z, psc[2][i], a);
                pacc[r][i] = fmaf(xv.w, psc[3][i], a);
            }
        }
        if (sh == 0) {                                   // ones-row: softmax denom
#pragma unroll
            for (int i = 0; i < 8; ++i)
                pones[i] += (psc[0][i] + psc[1][i]) + (psc[2][i] + psc[3][i]);
        }
    }

    // 4-lane jw reduction on VALU pipe
#pragma unroll
    for (int r = 0; r < 4; ++r)
#pragma unroll
        for (int i = 0; i < 8; ++i) pacc[r][i] = qsum(pacc[r][i]);
#pragma unroll
    for (int i = 0; i < 8; ++i) pones[i] = qsum(pones[i]);

    if (jw == 0) {
#pragma unroll
        for (int r = 0; r < 4; ++r) {
            int s = (sh << 2) + r;
            *(float4*)&hp[s * 68 + (w << 3)]     = make_float4(pacc[r][0], pacc[r][1], pacc[r][2], pacc[r][3]);
            *(float4*)&hp[s * 68 + (w << 3) + 4] = make_float4(pacc[r][4], pacc[r][5], pacc[r][6], pacc[r][7]);
        }
    }
    if ((t & 63) == 0) {                                 // lane 0: wave's denom partial
        *(float4*)&hp[64 * 68 + (w << 3)]     = make_float4(pones[0], pones[1], pones[2], pones[3]);
        *(float4*)&hp[64 * 68 + (w << 3) + 4] = make_float4(pones[4], pones[5], pones[6], pones[7]);
    }
    __syncthreads();

    if (t < IT) {
        float s = 0.f;
#pragma unroll
        for (int ww = 0; ww < 8; ++ww) s += hp[64 * 68 + (ww << 3) + t];
        s_inv[t] = 1.0f / s;
    }
    __syncthreads();

    // ---- h: combine 8 wave-partials, scale, sigmoid ----
    {
        int s = t >> 3, ip = t & 7;
        float h = 0.f;
#pragma unroll
        for (int ww = 0; ww < 8; ++ww) h += hp[s * 68 + (ww << 3) + ip];
        h *= s_inv[ip];
        out0[((size_t)(b * SS + s)) * NN + i0 + ip] = 1.0f / (1.0f + __expf(-h));
    }

    // ---- attention rows from fp32 pr (coalesced 256B per store) ----
#pragma unroll
    for (int i = 0; i < IT; ++i)
        out1[((size_t)(b * NN + i0 + i)) * NN + t] = pr[i] * s_inv[i];
}

extern "C" void kernel_launch(void* const* d_in, const int* in_sizes, int n_in,
                              void* d_out, int out_size, void* d_ws, size_t ws_size,
                              hipStream_t stream) {
    const float* x   = (const float*)d_in[0];
    const float* W   = (const float*)d_in[1];
    const float* b_w = (const float*)d_in[2];
    const float* Wa  = (const float*)d_in[3];

    float* out0 = (float*)d_out;                         // (B,S,N)
    float* out1 = (float*)d_out + (size_t)BB * SS * NN;  // (B,N,N)

    float* tip = (float*)d_ws;                           // (B,E,N)
    float* tjp = tip + (size_t)BB * EE * NN;             // (B,E,N)
    float* cip = tjp + (size_t)BB * EE * NN;             // (B,N)
    float* djp = cip + (size_t)BB * NN;                  // (B,N)

    proj_kernel<<<BB * (NN / 16), 256, 0, stream>>>(x, W, b_w, Wa, tip, tjp, cip, djp);
    attn_kernel<<<BB * (NN / IT), 512, 0, stream>>>(x, tip, tjp, cip, djp, Wa, out0, out1);
}

// Round 6
// 36.579 us; speedup vs baseline: 1.7187x; 1.7187x over previous
//
#include <hip/hip_runtime.h>
#include <math.h>

#define BB 8
#define SS 64
#define NN 512
#define EE 32
#define IT 8

__device__ __forceinline__ unsigned short f2bf(float f) {
    union { float f; unsigned u; } v; v.f = f;
    unsigned r = v.u + 0x7fffu + ((v.u >> 16) & 1u);   // RTNE
    return (unsigned short)(r >> 16);
}

__device__ __forceinline__ float qsum(float v) {      // sum over 4-lane quad (VALU pipe)
    v += __int_as_float(__builtin_amdgcn_mov_dpp(__float_as_int(v), 0xB1, 0xF, 0xF, true));
    v += __int_as_float(__builtin_amdgcn_mov_dpp(__float_as_int(v), 0x4E, 0xF, 0xF, true));
    return v;
}

// proj: tip[b][e][n] = ti' = x^T W_i^T + b_w, tjp[b][e][n] = tj   (layout B,E,N)
//       cip[b][n] = sum_e Wa[e]*ti'[n][e];  djp[b][n] = sum_e Wa[e]*tj[n][e]
__global__ __launch_bounds__(256) void proj_kernel(
    const float* __restrict__ x, const float* __restrict__ W,
    const float* __restrict__ b_w, const float* __restrict__ Wa,
    float* __restrict__ tip, float* __restrict__ tjp,
    float* __restrict__ cip, float* __restrict__ djp)
{
    __shared__ float sW[SS][65];
    const int t = threadIdx.x;
    const int wg = ((blockIdx.x & 7) << 5) | (blockIdx.x >> 3);  // XCD swizzle (256=8*32)
    const int b = wg >> 5;
    const int n0 = (wg & 31) << 4;

#pragma unroll
    for (int r = 0; r < 4; ++r) {   // stage W (4096 floats) as [s][eo]
        int idx = r * 1024 + t * 4;
        float4 w4 = *(const float4*)(W + idx);
        int e = idx >> 7;
        int sp = idx & 127;
        int eo = ((sp >> 6) << 5) | e;   // 0..31 ti, 32..63 tj
        int s0 = sp & 63;
        sW[s0 + 0][eo] = w4.x;
        sW[s0 + 1][eo] = w4.y;
        sW[s0 + 2][eo] = w4.z;
        sW[s0 + 3][eo] = w4.w;
    }
    __syncthreads();

    const int eo = t & 63;
    const int ng = t >> 6;
    const float* xb = x + (size_t)b * SS * NN + n0 + (ng << 2);
    float a0 = 0.f, a1 = 0.f, a2 = 0.f, a3 = 0.f;
#pragma unroll 8
    for (int s = 0; s < SS; ++s) {
        float wv = sW[s][eo];                               // conflict-free
        float4 xv = *(const float4*)(xb + (size_t)s * NN);  // wave-uniform bcast
        a0 = fmaf(wv, xv.x, a0);
        a1 = fmaf(wv, xv.y, a1);
        a2 = fmaf(wv, xv.z, a2);
        a3 = fmaf(wv, xv.w, a3);
    }
    const int e = eo & 31;
    const bool isI = eo < EE;
    float bias = isI ? b_w[e] : 0.f;
    a0 += bias; a1 += bias; a2 += bias; a3 += bias;
    float* dst = isI ? tip : tjp;
    *(float4*)(dst + ((size_t)(b * EE + e)) * NN + n0 + (ng << 2)) =
        make_float4(a0, a1, a2, a3);

    // rank-1 terms: reduce wa*val over each 32-lane half (xor<32 keeps halves apart)
    float wa = Wa[e];
    float r0 = wa * a0, r1 = wa * a1, r2 = wa * a2, r3 = wa * a3;
#pragma unroll
    for (int off = 1; off <= 16; off <<= 1) {
        r0 += __shfl_xor(r0, off);
        r1 += __shfl_xor(r1, off);
        r2 += __shfl_xor(r2, off);
        r3 += __shfl_xor(r3, off);
    }
    if (eo == 0)
        *(float4*)(cip + (size_t)b * NN + n0 + (ng << 2)) = make_float4(r0, r1, r2, r3);
    if (eo == 32)
        *(float4*)(djp + (size_t)b * NN + n0 + (ng << 2)) = make_float4(r0, r1, r2, r3);
}

// attn: block = (b, 8-i tile), 512 threads, 2 blocks/CU. LDS ~26 KB.
__global__ __launch_bounds__(512, 4) void attn_kernel(
    const float* __restrict__ x,
    const float* __restrict__ tip,
    const float* __restrict__ tjp,
    const float* __restrict__ cip,
    const float* __restrict__ djp,
    const float* __restrict__ Wa,
    float* __restrict__ out0,
    float* __restrict__ out1)
{
    __shared__ __align__(16) unsigned scT[NN * 4];   // 8 KB: row j = 8 bf16 (i 0..7)
    __shared__ __align__(16) float hp[SS * 68];      // [s][w*8+i], s-stride 68 (17.4 KB)
    __shared__ __align__(16) float red[8][8];        // [wave][i] denom partials
    __shared__ float s_inv[IT];

    const int t = threadIdx.x;
    const int wg = ((blockIdx.x & 7) << 6) | (blockIdx.x >> 3);  // XCD swizzle (512=8*64)
    const int b = wg >> 6;
    const int i0 = (wg & 63) << 3;
    const int lane = t & 63;
    const int w = t >> 6;

    // ---- scores: thread owns j = t; ti/ci/Wa via scalar loads (SGPR operands) ----
    const float* tjb = tjp + (size_t)b * EE * NN + t;
    const float* tib = tip + (size_t)b * EE * NN + i0;   // block-uniform -> s_load
    float acc[IT];
#pragma unroll
    for (int i = 0; i < IT; ++i) acc[i] = 0.f;

#pragma unroll
    for (int e = 0; e < EE; ++e) {
        float tjv = tjb[(size_t)e * NN];                 // coalesced L2
        float wa = Wa[e];                                // uniform
#pragma unroll
        for (int i = 0; i < IT; ++i) {
            float p = tib[e * NN + i] + tjv;             // sgpr + vgpr
            acc[i] = fmaf(fabsf(p), wa, acc[i]);         // |p| input-modifier
        }
    }

    // epilogue: sc = 0.4*acc + 0.6*(ci + dj); no-max softmax (|sc| < ~10)
    float dj = djp[(size_t)b * NN + t];
    const float* cib = cip + (size_t)b * NN + i0;        // uniform
    float pr[IT];
#pragma unroll
    for (int i = 0; i < IT; ++i) {
        float sc = fmaf(0.4f, acc[i], 0.6f * (cib[i] + dj));
        pr[i] = __expf(sc);
    }

    // pack 8 bf16 (unnormalized) -> one 16B row of scT
    {
        unsigned p0 = f2bf(pr[0]) | ((unsigned)f2bf(pr[1]) << 16);
        unsigned p1 = f2bf(pr[2]) | ((unsigned)f2bf(pr[3]) << 16);
        unsigned p2 = f2bf(pr[4]) | ((unsigned)f2bf(pr[5]) << 16);
        unsigned p3 = f2bf(pr[6]) | ((unsigned)f2bf(pr[7]) << 16);
        uint4 pk; pk.x = p0; pk.y = p1; pk.z = p2; pk.w = p3;
        *(uint4*)&scT[t << 2] = pk;
    }

    // ---- softmax denominators: exact fp32 butterfly + cross-wave combine ----
    float rs[IT];
#pragma unroll
    for (int i = 0; i < IT; ++i) rs[i] = pr[i];
#pragma unroll
    for (int off = 1; off <= 32; off <<= 1) {
#pragma unroll
        for (int i = 0; i < IT; ++i) rs[i] += __shfl_xor(rs[i], off);
    }
    if (lane == 0) {
        *(float4*)&red[w][0] = make_float4(rs[0], rs[1], rs[2], rs[3]);
        *(float4*)&red[w][4] = make_float4(rs[4], rs[5], rs[6], rs[7]);
    }
    __syncthreads();
    if (t < IT) {
        float S = 0.f;
#pragma unroll
        for (int ww = 0; ww < 8; ++ww) S += red[ww][t];
        s_inv[t] = 1.0f / S;
    }
    __syncthreads();                                     // s_inv + scT visible

    // ---- attention rows from fp32 pr (coalesced 2KB per i-row); pr dies here ----
#pragma unroll
    for (int i = 0; i < IT; ++i)
        out1[((size_t)(b * NN + i0 + i)) * NN + t] = pr[i] * s_inv[i];

    // ---- PV: wave w owns j in [w*64, w*64+64); lane = (jw, sh) ----
    const int jw = t & 3;
    const int sh = (t >> 2) & 15;

    float pacc[4][8];
#pragma unroll
    for (int r = 0; r < 4; ++r)
#pragma unroll
        for (int i = 0; i < 8; ++i) pacc[r][i] = 0.f;

    const float* xb = x + (size_t)b * SS * NN;
#pragma unroll
    for (int c4 = 0; c4 < 4; ++c4) {
        const int jseg = (w << 6) + (c4 << 4) + (jw << 2);
        float psc[4][8];
#pragma unroll
        for (int v = 0; v < 4; ++v) {                    // b128, 2-way banks = free
            uint4 d = *(const uint4*)&scT[(jseg + v) << 2];
            psc[v][0] = __uint_as_float(d.x << 16);
            psc[v][1] = __uint_as_float(d.x & 0xffff0000u);
            psc[v][2] = __uint_as_float(d.y << 16);
            psc[v][3] = __uint_as_float(d.y & 0xffff0000u);
            psc[v][4] = __uint_as_float(d.z << 16);
            psc[v][5] = __uint_as_float(d.z & 0xffff0000u);
            psc[v][6] = __uint_as_float(d.w << 16);
            psc[v][7] = __uint_as_float(d.w & 0xffff0000u);
        }
#pragma unroll
        for (int r = 0; r < 4; ++r) {
            int s = (sh << 2) + r;
            float4 xv = *(const float4*)(xb + (size_t)s * NN + jseg);  // L2 direct
#pragma unroll
            for (int i = 0; i < 8; ++i) {
                float a = fmaf(xv.x, psc[0][i], pacc[r][i]);
                a = fmaf(xv.y, psc[1][i], a);
                a = fmaf(xv.z, psc[2][i], a);
                pacc[r][i] = fmaf(xv.w, psc[3][i], a);
            }
        }
    }

    // 4-lane jw reduction on VALU pipe
#pragma unroll
    for (int r = 0; r < 4; ++r)
#pragma unroll
        for (int i = 0; i < 8; ++i) pacc[r][i] = qsum(pacc[r][i]);

    if (jw == 0) {
#pragma unroll
        for (int r = 0; r < 4; ++r) {
            int s = (sh << 2) + r;
            *(float4*)&hp[s * 68 + (w << 3)]     = make_float4(pacc[r][0], pacc[r][1], pacc[r][2], pacc[r][3]);
            *(float4*)&hp[s * 68 + (w << 3) + 4] = make_float4(pacc[r][4], pacc[r][5], pacc[r][6], pacc[r][7]);
        }
    }
    __syncthreads();

    // ---- h: combine 8 wave-partials, scale by inv, sigmoid ----
    {
        int s = t >> 3, ip = t & 7;
        float h = 0.f;
#pragma unroll
        for (int ww = 0; ww < 8; ++ww) h += hp[s * 68 + (ww << 3) + ip];
        h *= s_inv[ip];
        out0[((size_t)(b * SS + s)) * NN + i0 + ip] = 1.0f / (1.0f + __expf(-h));
    }
}

extern "C" void kernel_launch(void* const* d_in, const int* in_sizes, int n_in,
                              void* d_out, int out_size, void* d_ws, size_t ws_size,
                              hipStream_t stream) {
    const float* x   = (const float*)d_in[0];
    const float* W   = (const float*)d_in[1];
    const float* b_w = (const float*)d_in[2];
    const float* Wa  = (const float*)d_in[3];

    float* out0 = (float*)d_out;                         // (B,S,N)
    float* out1 = (float*)d_out + (size_t)BB * SS * NN;  // (B,N,N)

    float* tip = (float*)d_ws;                           // (B,E,N)
    float* tjp = tip + (size_t)BB * EE * NN;             // (B,E,N)
    float* cip = tjp + (size_t)BB * EE * NN;             // (B,N)
    float* djp = cip + (size_t)BB * NN;                  // (B,N)

    proj_kernel<<<BB * (NN / 16), 256, 0, stream>>>(x, W, b_w, Wa, tip, tjp, cip, djp);
    attn_kernel<<<BB * (NN / IT), 512, 0, stream>>>(x, tip, tjp, cip, djp, Wa, out0, out1);
}

// Round 7
// 27.027 us; speedup vs baseline: 2.3261x; 1.3534x over previous
//
#include <hip/hip_runtime.h>
#include <math.h>

#define BB 8
#define SS 64
#define NN 512
#define EE 32
#define IT 8

__device__ __forceinline__ unsigned short f2bf(float f) {
    union { float f; unsigned u; } v; v.f = f;
    unsigned r = v.u + 0x7fffu + ((v.u >> 16) & 1u);   // RTNE
    return (unsigned short)(r >> 16);
}

__device__ __forceinline__ float qsum(float v) {      // sum over 4-lane quad (VALU pipe)
    v += __int_as_float(__builtin_amdgcn_mov_dpp(__float_as_int(v), 0xB1, 0xF, 0xF, true));
    v += __int_as_float(__builtin_amdgcn_mov_dpp(__float_as_int(v), 0x4E, 0xF, 0xF, true));
    return v;
}

// proj: tip[b][e][n] = ti' = x^T W_i^T + b_w, tjp[b][e][n] = tj   (layout B,E,N)
//       cip[b][n] = sum_e Wa[e]*ti'[n][e];  djp[b][n] = sum_e Wa[e]*tj[n][e]
__global__ __launch_bounds__(256) void proj_kernel(
    const float* __restrict__ x, const float* __restrict__ W,
    const float* __restrict__ b_w, const float* __restrict__ Wa,
    float* __restrict__ tip, float* __restrict__ tjp,
    float* __restrict__ cip, float* __restrict__ djp)
{
    __shared__ float sW[SS][65];
    const int t = threadIdx.x;
    const int wg = ((blockIdx.x & 7) << 5) | (blockIdx.x >> 3);  // XCD swizzle (256=8*32)
    const int b = wg >> 5;
    const int n0 = (wg & 31) << 4;

#pragma unroll
    for (int r = 0; r < 4; ++r) {   // stage W (4096 floats) as [s][eo]
        int idx = r * 1024 + t * 4;
        float4 w4 = *(const float4*)(W + idx);
        int e = idx >> 7;
        int sp = idx & 127;
        int eo = ((sp >> 6) << 5) | e;   // 0..31 ti, 32..63 tj
        int s0 = sp & 63;
        sW[s0 + 0][eo] = w4.x;
        sW[s0 + 1][eo] = w4.y;
        sW[s0 + 2][eo] = w4.z;
        sW[s0 + 3][eo] = w4.w;
    }
    __syncthreads();

    const int eo = t & 63;
    const int ng = t >> 6;
    const float* xb = x + (size_t)b * SS * NN + n0 + (ng << 2);
    float a0 = 0.f, a1 = 0.f, a2 = 0.f, a3 = 0.f;
#pragma unroll 8
    for (int s = 0; s < SS; ++s) {
        float wv = sW[s][eo];                               // conflict-free
        float4 xv = *(const float4*)(xb + (size_t)s * NN);  // wave-uniform bcast
        a0 = fmaf(wv, xv.x, a0);
        a1 = fmaf(wv, xv.y, a1);
        a2 = fmaf(wv, xv.z, a2);
        a3 = fmaf(wv, xv.w, a3);
    }
    const int e = eo & 31;
    const bool isI = eo < EE;
    float bias = isI ? b_w[e] : 0.f;
    a0 += bias; a1 += bias; a2 += bias; a3 += bias;
    float* dst = isI ? tip : tjp;
    *(float4*)(dst + ((size_t)(b * EE + e)) * NN + n0 + (ng << 2)) =
        make_float4(a0, a1, a2, a3);

    // rank-1 terms: reduce wa*val over each 32-lane half (xor<32 keeps halves apart)
    float wa = Wa[e];
    float r0 = wa * a0, r1 = wa * a1, r2 = wa * a2, r3 = wa * a3;
#pragma unroll
    for (int off = 1; off <= 16; off <<= 1) {
        r0 += __shfl_xor(r0, off);
        r1 += __shfl_xor(r1, off);
        r2 += __shfl_xor(r2, off);
        r3 += __shfl_xor(r3, off);
    }
    if (eo == 0)
        *(float4*)(cip + (size_t)b * NN + n0 + (ng << 2)) = make_float4(r0, r1, r2, r3);
    if (eo == 32)
        *(float4*)(djp + (size_t)b * NN + n0 + (ng << 2)) = make_float4(r0, r1, r2, r3);
}

// attn: block = (b, 8-i tile), 512 threads. LDS ~26 KB.
// NOTE: (512, 2) not (512, 4): empirically (512,4) caps VGPR at 64 -> PV live
// set (~90) spills to scratch (R5: FETCH 75MB, WRITE 127MB, VGPR_Count=64).
__global__ __launch_bounds__(512, 2) void attn_kernel(
    const float* __restrict__ x,
    const float* __restrict__ tip,
    const float* __restrict__ tjp,
    const float* __restrict__ cip,
    const float* __restrict__ djp,
    const float* __restrict__ Wa,
    float* __restrict__ out0,
    float* __restrict__ out1)
{
    __shared__ __align__(16) unsigned scT[NN * 4];   // 8 KB: row j = 8 bf16 (i 0..7)
    __shared__ __align__(16) float hp[SS * 68];      // [s][w*8+i], s-stride 68 (17.4 KB)
    __shared__ __align__(16) float red[8][8];        // [wave][i] denom partials
    __shared__ float s_inv[IT];

    const int t = threadIdx.x;
    const int wg = ((blockIdx.x & 7) << 6) | (blockIdx.x >> 3);  // XCD swizzle (512=8*64)
    const int b = wg >> 6;
    const int i0 = (wg & 63) << 3;
    const int lane = t & 63;
    const int w = t >> 6;

    // ---- scores: thread owns j = t; ti/ci/Wa via scalar loads (SGPR operands) ----
    const float* tjb = tjp + (size_t)b * EE * NN + t;
    const float* tib = tip + (size_t)b * EE * NN + i0;   // block-uniform -> s_load
    float acc[IT];
#pragma unroll
    for (int i = 0; i < IT; ++i) acc[i] = 0.f;

#pragma unroll
    for (int e = 0; e < EE; ++e) {
        float tjv = tjb[(size_t)e * NN];                 // coalesced L2
        float wa = Wa[e];                                // uniform
#pragma unroll
        for (int i = 0; i < IT; ++i) {
            float p = tib[e * NN + i] + tjv;             // sgpr + vgpr
            acc[i] = fmaf(fabsf(p), wa, acc[i]);         // |p| input-modifier
        }
    }

    // epilogue: sc = 0.4*acc + 0.6*(ci + dj); no-max softmax (|sc| < ~10)
    float dj = djp[(size_t)b * NN + t];
    const float* cib = cip + (size_t)b * NN + i0;        // uniform
    float pr[IT];
#pragma unroll
    for (int i = 0; i < IT; ++i) {
        float sc = fmaf(0.4f, acc[i], 0.6f * (cib[i] + dj));
        pr[i] = __expf(sc);
    }

    // pack 8 bf16 (unnormalized) -> one 16B row of scT
    {
        unsigned p0 = f2bf(pr[0]) | ((unsigned)f2bf(pr[1]) << 16);
        unsigned p1 = f2bf(pr[2]) | ((unsigned)f2bf(pr[3]) << 16);
        unsigned p2 = f2bf(pr[4]) | ((unsigned)f2bf(pr[5]) << 16);
        unsigned p3 = f2bf(pr[6]) | ((unsigned)f2bf(pr[7]) << 16);
        uint4 pk; pk.x = p0; pk.y = p1; pk.z = p2; pk.w = p3;
        *(uint4*)&scT[t << 2] = pk;
    }

    // ---- softmax denominators: exact fp32 butterfly + cross-wave combine ----
    float rs[IT];
#pragma unroll
    for (int i = 0; i < IT; ++i) rs[i] = pr[i];
#pragma unroll
    for (int off = 1; off <= 32; off <<= 1) {
#pragma unroll
        for (int i = 0; i < IT; ++i) rs[i] += __shfl_xor(rs[i], off);
    }
    if (lane == 0) {
        *(float4*)&red[w][0] = make_float4(rs[0], rs[1], rs[2], rs[3]);
        *(float4*)&red[w][4] = make_float4(rs[4], rs[5], rs[6], rs[7]);
    }
    __syncthreads();
    if (t < IT) {
        float S = 0.f;
#pragma unroll
        for (int ww = 0; ww < 8; ++ww) S += red[ww][t];
        s_inv[t] = 1.0f / S;
    }
    __syncthreads();                                     // s_inv + scT visible

    // ---- attention rows from fp32 pr (coalesced 2KB per i-row); pr dies here ----
#pragma unroll
    for (int i = 0; i < IT; ++i)
        out1[((size_t)(b * NN + i0 + i)) * NN + t] = pr[i] * s_inv[i];

    // ---- PV: wave w owns j in [w*64, w*64+64); lane = (jw, sh) ----
    const int jw = t & 3;
    const int sh = (t >> 2) & 15;

    float pacc[4][8];
#pragma unroll
    for (int r = 0; r < 4; ++r)
#pragma unroll
        for (int i = 0; i < 8; ++i) pacc[r][i] = 0.f;

    const float* xb = x + (size_t)b * SS * NN;
#pragma unroll
    for (int c4 = 0; c4 < 4; ++c4) {
        const int jseg = (w << 6) + (c4 << 4) + (jw << 2);
        float psc[4][8];
#pragma unroll
        for (int v = 0; v < 4; ++v) {                    // b128, 2-way banks = free
            uint4 d = *(const uint4*)&scT[(jseg + v) << 2];
            psc[v][0] = __uint_as_float(d.x << 16);
            psc[v][1] = __uint_as_float(d.x & 0xffff0000u);
            psc[v][2] = __uint_as_float(d.y << 16);
            psc[v][3] = __uint_as_float(d.y & 0xffff0000u);
            psc[v][4] = __uint_as_float(d.z << 16);
            psc[v][5] = __uint_as_float(d.z & 0xffff0000u);
            psc[v][6] = __uint_as_float(d.w << 16);
            psc[v][7] = __uint_as_float(d.w & 0xffff0000u);
        }
#pragma unroll
        for (int r = 0; r < 4; ++r) {
            int s = (sh << 2) + r;
            float4 xv = *(const float4*)(xb + (size_t)s * NN + jseg);  // L2 direct
#pragma unroll
            for (int i = 0; i < 8; ++i) {
                float a = fmaf(xv.x, psc[0][i], pacc[r][i]);
                a = fmaf(xv.y, psc[1][i], a);
                a = fmaf(xv.z, psc[2][i], a);
                pacc[r][i] = fmaf(xv.w, psc[3][i], a);
            }
        }
    }

    // 4-lane jw reduction on VALU pipe
#pragma unroll
    for (int r = 0; r < 4; ++r)
#pragma unroll
        for (int i = 0; i < 8; ++i) pacc[r][i] = qsum(pacc[r][i]);

    if (jw == 0) {
#pragma unroll
        for (int r = 0; r < 4; ++r) {
            int s = (sh << 2) + r;
            *(float4*)&hp[s * 68 + (w << 3)]     = make_float4(pacc[r][0], pacc[r][1], pacc[r][2], pacc[r][3]);
            *(float4*)&hp[s * 68 + (w << 3) + 4] = make_float4(pacc[r][4], pacc[r][5], pacc[r][6], pacc[r][7]);
        }
    }
    __syncthreads();

    // ---- h: combine 8 wave-partials, scale by inv, sigmoid ----
    {
        int s = t >> 3, ip = t & 7;
        float h = 0.f;
#pragma unroll
        for (int ww = 0; ww < 8; ++ww) h += hp[s * 68 + (ww << 3) + ip];
        h *= s_inv[ip];
        out0[((size_t)(b * SS + s)) * NN + i0 + ip] = 1.0f / (1.0f + __expf(-h));
    }
}

extern "C" void kernel_launch(void* const* d_in, const int* in_sizes, int n_in,
                              void* d_out, int out_size, void* d_ws, size_t ws_size,
                              hipStream_t stream) {
    const float* x   = (const float*)d_in[0];
    const float* W   = (const float*)d_in[1];
    const float* b_w = (const float*)d_in[2];
    const float* Wa  = (const float*)d_in[3];

    float* out0 = (float*)d_out;                         // (B,S,N)
    float* out1 = (float*)d_out + (size_t)BB * SS * NN;  // (B,N,N)

    float* tip = (float*)d_ws;                           // (B,E,N)
    float* tjp = tip + (size_t)BB * EE * NN;             // (B,E,N)
    float* cip = tjp + (size_t)BB * EE * NN;             // (B,N)
    float* djp = cip + (size_t)BB * NN;                  // (B,N)

    proj_kernel<<<BB * (NN / 16), 256, 0, stream>>>(x, W, b_w, Wa, tip, tjp, cip, djp);
    attn_kernel<<<BB * (NN / IT), 512, 0, stream>>>(x, tip, tjp, cip, djp, Wa, out0, out1);
}